// Round 1
// baseline (1516.567 us; speedup 1.0000x reference)
//
#include <hip/hip_runtime.h>

#define C64 64
#define HWSZ 65536
#define NBATCH 16
#define NTOT (NBATCH * C64 * HWSZ)   // 67108864

// workspace layout (bytes)
#define OFF_SLOTS  0                        // 4 x uint   amax slots: x, y1, y3, y4
#define OFF_SCALES 16                       // 4 x float  weight scales
#define OFF_WQP1   64                       // 4096 _Float16 (integer-valued quant levels)
#define OFF_WQP2   (OFF_WQP1 + 4096 * 2)
#define OFF_WQF1   (OFF_WQP2 + 4096 * 2)    // 576 float (dequantized)
#define OFF_WQF2   (OFF_WQF1 + 576 * 4)
#define OFF_BUF    ((OFF_WQF2 + 576 * 4 + 255) & ~255)   // 67108864 floats

typedef __attribute__((ext_vector_type(8))) _Float16 f16x8;
typedef __attribute__((ext_vector_type(4))) float f32x4;

#define LDSX_S 66   // x-tile row stride in f16: 132 B -> bank step 33 dwords == 1 (mod 32)

__device__ inline float block_amax_256(const float* p, int n, float* red) {
  float m = 0.f;
  for (int i = threadIdx.x; i < n; i += 256) m = fmaxf(m, fabsf(p[i]));
  red[threadIdx.x] = m;
  __syncthreads();
  for (int s = 128; s > 0; s >>= 1) {
    if ((int)threadIdx.x < s) red[threadIdx.x] = fmaxf(red[threadIdx.x], red[threadIdx.x + s]);
    __syncthreads();
  }
  float r = red[0];
  __syncthreads();
  return r;
}

// one block: zero amax slots, fake-quant all weights
__global__ __launch_bounds__(256) void prep_kernel(
    const float* __restrict__ wp1, const float* __restrict__ wf1,
    const float* __restrict__ wp2, const float* __restrict__ wf2,
    unsigned* __restrict__ slots, float* __restrict__ scales,
    _Float16* __restrict__ wqp1, _Float16* __restrict__ wqp2,
    float* __restrict__ wqf1, float* __restrict__ wqf2) {
  __shared__ float red[256];
  const int t = threadIdx.x;
  if (t < 4) slots[t] = 0u;

  float a = block_amax_256(wp1, 4096, red);
  float s = a / 7.f + 1e-12f;
  if (t == 0) scales[0] = s;
  for (int i = t; i < 4096; i += 256) {
    float r = fminf(fmaxf(rintf(wp1[i] / s), -7.f), 7.f);
    wqp1[i] = (_Float16)r;     // store integer level, scale folded in epilogue
  }

  a = block_amax_256(wp2, 4096, red);
  s = a / 7.f + 1e-12f;
  if (t == 0) scales[2] = s;
  for (int i = t; i < 4096; i += 256) {
    float r = fminf(fmaxf(rintf(wp2[i] / s), -7.f), 7.f);
    wqp2[i] = (_Float16)r;
  }

  a = block_amax_256(wf1, 576, red);
  s = a / 7.f + 1e-12f;
  for (int i = t; i < 576; i += 256) {
    float r = fminf(fmaxf(rintf(wf1[i] / s), -7.f), 7.f);
    wqf1[i] = r * s;           // dequantized for VALU depthwise conv
  }

  a = block_amax_256(wf2, 576, red);
  s = a / 7.f + 1e-12f;
  for (int i = t; i < 576; i += 256) {
    float r = fminf(fmaxf(rintf(wf2[i] / s), -7.f), 7.f);
    wqf2[i] = r * s;
  }
}

// global amax of x (float4 grid-stride)
__global__ __launch_bounds__(256) void amax_kernel(const float4* __restrict__ x, int n4,
                                                   unsigned* __restrict__ slot) {
  float m = 0.f;
  const int stride = gridDim.x * blockDim.x;
  for (int i = blockIdx.x * blockDim.x + threadIdx.x; i < n4; i += stride) {
    float4 v = x[i];
    m = fmaxf(m, fmaxf(fmaxf(fabsf(v.x), fabsf(v.y)), fmaxf(fabsf(v.z), fabsf(v.w))));
  }
  for (int off = 32; off; off >>= 1) m = fmaxf(m, __shfl_down(m, off));
  __shared__ float wred[4];
  if ((threadIdx.x & 63) == 0) wred[threadIdx.x >> 6] = m;
  __syncthreads();
  if (threadIdx.x == 0) {
    m = fmaxf(fmaxf(wred[0], wred[1]), fmaxf(wred[2], wred[3]));
    atomicMax(slot, __float_as_uint(m));
  }
}

// read f16x8 from LDS at 4-byte-aligned (not 16-byte-aligned) address
__device__ inline f16x8 lds_ld8(const _Float16* p) {
  union { unsigned u[4]; f16x8 h; } r;
  const unsigned* q = (const unsigned*)p;
  r.u[0] = q[0]; r.u[1] = q[1]; r.u[2] = q[2]; r.u[3] = q[3];
  return r.h;
}

// 1x1 conv as integer-exact f16 MFMA GEMM: out[co][pos] = s_in*s_w * sum_ci rw[co][ci]*rx[ci][pos]
// block: 128 positions x 64 co; 4 waves, wave w handles co [16w,16w+16)
// staging: 16 independent float2 loads -> regs -> quant -> LDS [pos][ci] stride 66 (conflict-free)
__global__ __launch_bounds__(256) void conv1x1_kernel(
    const float* __restrict__ in, float* __restrict__ out,
    const _Float16* __restrict__ wq, const float* __restrict__ sw_ptr,
    const unsigned* __restrict__ sin_slot, unsigned* __restrict__ amax_out) {
  __shared__ _Float16 lds_x[128 * LDSX_S];   // [pos][ci], stride 66
  __shared__ float wred[4];

  const int tid = threadIdx.x;
  const int p0 = blockIdx.x * 128;
  const int b = p0 >> 16;          // HWSZ = 65536 positions per batch-plane
  const int hw0 = p0 & 65535;
  const float* xin = in + (size_t)b * C64 * HWSZ + hw0;

  const int wv = tid >> 6;
  const int lane = tid & 63;
  const int l15 = lane & 15;
  const int quad = lane >> 4;
  const int cw = wv * 16;

  // A fragments (integer weight levels) straight from global: 8 KB, L1/L2 resident.
  // A[m=lane&15][k=quad*8+j], k = ci
  f16x8 a0 = *(const f16x8*)(wq + (cw + l15) * 64 + quad * 8);
  f16x8 a1 = *(const f16x8*)(wq + (cw + l15) * 64 + 32 + quad * 8);

  // issue all 16 staging loads up front (independent, pipelined in flight)
  // iter i: wave wv covers full 128-pos row of ci = i*4 + wv, lane -> pos 2*lane
  float2 v[16];
  #pragma unroll
  for (int i = 0; i < 16; i++) {
    const int idx = i * 256 + tid;
    const int ci = idx >> 6;            // wave-uniform
    const int pz = (idx & 63) * 2;      // per-lane position
    v[i] = *(const float2*)(xin + (size_t)ci * HWSZ + pz);
  }

  const float amax_in = __uint_as_float(*sin_slot);
  const float s_in = amax_in / 127.f + 1e-12f;
  const float inv_s = 1.f / s_in;

  // quantize + transpose-write to LDS: rows 2l, 2l+1 -> bank step 2 (mod 32): conflict-free
  #pragma unroll
  for (int i = 0; i < 16; i++) {
    const int idx = i * 256 + tid;
    const int ci = idx >> 6;
    const int pz = (idx & 63) * 2;
    float r0 = fminf(fmaxf(rintf(v[i].x * inv_s), -127.f), 127.f);
    float r1 = fminf(fmaxf(rintf(v[i].y * inv_s), -127.f), 127.f);
    lds_x[(pz + 0) * LDSX_S + ci] = (_Float16)r0;
    lds_x[(pz + 1) * LDSX_S + ci] = (_Float16)r1;
  }
  __syncthreads();

  f32x4 acc[8];
  #pragma unroll
  for (int nt = 0; nt < 8; nt++) {
    const _Float16* bp = lds_x + (nt * 16 + l15) * LDSX_S + quad * 8;
    f16x8 b0 = lds_ld8(bp);        // B[k=quad*8+j][n=l15], k = ci
    f16x8 b1 = lds_ld8(bp + 32);
    f32x4 c = {0.f, 0.f, 0.f, 0.f};
    c = __builtin_amdgcn_mfma_f32_16x16x32_f16(a0, b0, c, 0, 0, 0);
    c = __builtin_amdgcn_mfma_f32_16x16x32_f16(a1, b1, c, 0, 0, 0);
    acc[nt] = c;
  }

  const float sw = *sw_ptr;
  const float sout = s_in * sw;
  float m = 0.f;
  float* outb = out + (size_t)b * C64 * HWSZ + hw0;
  #pragma unroll
  for (int nt = 0; nt < 8; nt++) {
    const int pp = nt * 16 + l15;
    #pragma unroll
    for (int r = 0; r < 4; r++) {
      const int co = cw + quad * 4 + r;   // C layout: col=lane&15, row=quad*4+reg
      float vv = acc[nt][r] * sout;
      outb[(size_t)co * HWSZ + pp] = vv;
      m = fmaxf(m, fabsf(vv));
    }
  }
  for (int off = 32; off; off >>= 1) m = fmaxf(m, __shfl_down(m, off));
  if (lane == 0) wred[wv] = m;
  __syncthreads();
  if (tid == 0)
    atomicMax(amax_out, __float_as_uint(fmaxf(fmaxf(wred[0], wred[1]), fmaxf(wred[2], wred[3]))));
}

// depthwise 3x3 (quantized input) + prelu (+ optional residual) (+ optional amax)
template <bool FUSE_RES>
__global__ __launch_bounds__(256) void dwconv_kernel(
    const float* __restrict__ in, float* __restrict__ out,
    const float* __restrict__ wq9, const float* __restrict__ alpha,
    const unsigned* __restrict__ sin_slot, unsigned* __restrict__ amax_out,
    const float* __restrict__ resid) {
  __shared__ float wred[4];
  const int strip = blockIdx.x & 7;        // 8 strips of 32 rows
  const int bc = blockIdx.x >> 3;          // 0..1023
  const int ch = bc & 63;
  const float* W9 = wq9 + ch * 9;
  const float w00 = W9[0], w01 = W9[1], w02 = W9[2];
  const float w10 = W9[3], w11 = W9[4], w12 = W9[5];
  const float w20 = W9[6], w21 = W9[7], w22 = W9[8];
  const float al = alpha[ch];
  const float amax_in = __uint_as_float(*sin_slot);
  const float s = amax_in / 127.f + 1e-12f;
  const float inv_s = 1.f / s;
  const float* base = in + (size_t)bc * HWSZ;
  float* ob = out + (size_t)bc * HWSZ;
  const float* rb = resid + (size_t)bc * HWSZ;   // only read if FUSE_RES
  const int c = threadIdx.x;                     // column 0..255
  const int r0 = strip * 32;

  auto qz = [&](float v) {
    return fminf(fmaxf(rintf(v * inv_s), -127.f), 127.f) * s;
  };

  float aL, aC, aR, bL, bC, bR, cL, cC, cR;
  auto ldrow = [&](int r, float& L, float& Cv, float& R) {
    if ((unsigned)r > 255u) { L = 0.f; Cv = 0.f; R = 0.f; return; }
    const float* rp = base + r * 256;
    Cv = qz(rp[c]);
    L = (c > 0) ? qz(rp[c - 1]) : 0.f;
    R = (c < 255) ? qz(rp[c + 1]) : 0.f;
  };

  ldrow(r0 - 1, aL, aC, aR);
  ldrow(r0, bL, bC, bR);
  float m = 0.f;
  for (int r = r0; r < r0 + 32; r++) {
    ldrow(r + 1, cL, cC, cR);
    float o = w00 * aL + w01 * aC + w02 * aR
            + w10 * bL + w11 * bC + w12 * bR
            + w20 * cL + w21 * cC + w22 * cR;
    o = (o > 0.f) ? o : al * o;
    if (FUSE_RES) o += rb[r * 256 + c];
    ob[r * 256 + c] = o;
    m = fmaxf(m, fabsf(o));
    aL = bL; aC = bC; aR = bR;
    bL = cL; bC = cC; bR = cR;
  }
  if (amax_out != nullptr) {
    for (int off = 32; off; off >>= 1) m = fmaxf(m, __shfl_down(m, off));
    if ((c & 63) == 0) wred[c >> 6] = m;
    __syncthreads();
    if (c == 0)
      atomicMax(amax_out, __float_as_uint(fmaxf(fmaxf(wred[0], wred[1]), fmaxf(wred[2], wred[3]))));
  }
}

extern "C" void kernel_launch(void* const* d_in, const int* in_sizes, int n_in,
                              void* d_out, int out_size, void* d_ws, size_t ws_size,
                              hipStream_t stream) {
  const float* x   = (const float*)d_in[0];
  const float* wp1 = (const float*)d_in[1];
  const float* wf1 = (const float*)d_in[2];
  const float* wp2 = (const float*)d_in[3];
  const float* wf2 = (const float*)d_in[4];
  const float* al1 = (const float*)d_in[5];
  const float* al2 = (const float*)d_in[6];
  float* out = (float*)d_out;

  char* ws = (char*)d_ws;
  unsigned* slots   = (unsigned*)(ws + OFF_SLOTS);
  float* scales     = (float*)(ws + OFF_SCALES);
  _Float16* wqp1    = (_Float16*)(ws + OFF_WQP1);
  _Float16* wqp2    = (_Float16*)(ws + OFF_WQP2);
  float* wqf1       = (float*)(ws + OFF_WQF1);
  float* wqf2       = (float*)(ws + OFF_WQF2);
  float* buf        = (float*)(ws + OFF_BUF);

  // 1. weight quant + slot init
  prep_kernel<<<1, 256, 0, stream>>>(wp1, wf1, wp2, wf2, slots, scales,
                                     wqp1, wqp2, wqf1, wqf2);
  // 2. amax(x) -> slot0
  amax_kernel<<<4096, 256, 0, stream>>>((const float4*)x, NTOT / 4, slots + 0);
  // 3. p1: x -> buf (y1), amax -> slot1
  conv1x1_kernel<<<NTOT / C64 / 128, 256, 0, stream>>>(x, buf, wqp1, scales + 0,
                                                       slots + 0, slots + 1);
  // 4. dw1 + prelu: buf -> out (y3), amax -> slot2
  dwconv_kernel<false><<<NBATCH * C64 * 8, 256, 0, stream>>>(buf, out, wqf1, al1,
                                                             slots + 1, slots + 2, nullptr);
  // 5. p2: out -> buf (y4), amax -> slot3
  conv1x1_kernel<<<NTOT / C64 / 128, 256, 0, stream>>>(out, buf, wqp2, scales + 2,
                                                       slots + 2, slots + 3);
  // 6. dw2 + prelu + residual: buf + x -> out
  dwconv_kernel<true><<<NBATCH * C64 * 8, 256, 0, stream>>>(buf, out, wqf2, al2,
                                                            slots + 3, nullptr, x);
}

// Round 2
// 1107.857 us; speedup vs baseline: 1.3689x; 1.3689x over previous
//
#include <hip/hip_runtime.h>

#define C64 64
#define HWSZ 65536
#define NBATCH 16
#define NTOT (NBATCH * C64 * HWSZ)   // 67108864

// amax slot arrays: 4 stages x 64 slots, each slot on its own 64B line
#define NSLOT 64
#define SLOT_U 16                            // uints per slot (64 B)
#define SLOTS_UINTS (4 * NSLOT * SLOT_U)     // 4096 uints = 16 KB

// workspace layout (bytes)
#define OFF_SLOTS  0                                  // 16 KB slot arrays
#define OFF_SCALES (SLOTS_UINTS * 4)                  // 4 x float weight scales
#define OFF_WQP1   (OFF_SCALES + 64)                  // 4096 _Float16 (integer levels)
#define OFF_WQP2   (OFF_WQP1 + 4096 * 2)
#define OFF_WQF1   (OFF_WQP2 + 4096 * 2)              // 576 float (dequantized)
#define OFF_WQF2   (OFF_WQF1 + 576 * 4)
#define OFF_BUF    ((OFF_WQF2 + 576 * 4 + 255) & ~255)   // 67108864 floats

typedef __attribute__((ext_vector_type(8))) _Float16 f16x8;
typedef __attribute__((ext_vector_type(4))) float f32x4;

#define LDSX_S 66   // x-tile row stride in f16: 132 B -> bank step 1 (mod 32)

// reduce a 64-slot amax array within one wave; every lane returns the max
__device__ inline float slots_amax_wave(const unsigned* __restrict__ sl) {
  const int lane = threadIdx.x & 63;
  float m = __uint_as_float(sl[lane * SLOT_U]);
  #pragma unroll
  for (int off = 32; off; off >>= 1) m = fmaxf(m, __shfl_down(m, off));
  return __shfl(m, 0);
}

__device__ inline float block_amax_256(const float* p, int n, float* red) {
  float m = 0.f;
  for (int i = threadIdx.x; i < n; i += 256) m = fmaxf(m, fabsf(p[i]));
  red[threadIdx.x] = m;
  __syncthreads();
  for (int s = 128; s > 0; s >>= 1) {
    if ((int)threadIdx.x < s) red[threadIdx.x] = fmaxf(red[threadIdx.x], red[threadIdx.x + s]);
    __syncthreads();
  }
  float r = red[0];
  __syncthreads();
  return r;
}

// one block: zero amax slot arrays, fake-quant all weights
__global__ __launch_bounds__(256) void prep_kernel(
    const float* __restrict__ wp1, const float* __restrict__ wf1,
    const float* __restrict__ wp2, const float* __restrict__ wf2,
    unsigned* __restrict__ slots, float* __restrict__ scales,
    _Float16* __restrict__ wqp1, _Float16* __restrict__ wqp2,
    float* __restrict__ wqf1, float* __restrict__ wqf2) {
  __shared__ float red[256];
  const int t = threadIdx.x;
  for (int i = t; i < SLOTS_UINTS; i += 256) slots[i] = 0u;

  float a = block_amax_256(wp1, 4096, red);
  float s = a / 7.f + 1e-12f;
  if (t == 0) scales[0] = s;
  for (int i = t; i < 4096; i += 256) {
    float r = fminf(fmaxf(rintf(wp1[i] / s), -7.f), 7.f);
    wqp1[i] = (_Float16)r;     // store integer level, scale folded in epilogue
  }

  a = block_amax_256(wp2, 4096, red);
  s = a / 7.f + 1e-12f;
  if (t == 0) scales[2] = s;
  for (int i = t; i < 4096; i += 256) {
    float r = fminf(fmaxf(rintf(wp2[i] / s), -7.f), 7.f);
    wqp2[i] = (_Float16)r;
  }

  a = block_amax_256(wf1, 576, red);
  s = a / 7.f + 1e-12f;
  for (int i = t; i < 576; i += 256) {
    float r = fminf(fmaxf(rintf(wf1[i] / s), -7.f), 7.f);
    wqf1[i] = r * s;           // dequantized for VALU depthwise conv
  }

  a = block_amax_256(wf2, 576, red);
  s = a / 7.f + 1e-12f;
  for (int i = t; i < 576; i += 256) {
    float r = fminf(fmaxf(rintf(wf2[i] / s), -7.f), 7.f);
    wqf2[i] = r * s;
  }
}

// global amax of x (float4 grid-stride) -> 64-slot spread
__global__ __launch_bounds__(256) void amax_kernel(const float4* __restrict__ x, int n4,
                                                   unsigned* __restrict__ slot) {
  float m = 0.f;
  const int stride = gridDim.x * blockDim.x;
  for (int i = blockIdx.x * blockDim.x + threadIdx.x; i < n4; i += stride) {
    float4 v = x[i];
    m = fmaxf(m, fmaxf(fmaxf(fabsf(v.x), fabsf(v.y)), fmaxf(fabsf(v.z), fabsf(v.w))));
  }
  for (int off = 32; off; off >>= 1) m = fmaxf(m, __shfl_down(m, off));
  __shared__ float wred[4];
  if ((threadIdx.x & 63) == 0) wred[threadIdx.x >> 6] = m;
  __syncthreads();
  if (threadIdx.x == 0) {
    m = fmaxf(fmaxf(wred[0], wred[1]), fmaxf(wred[2], wred[3]));
    atomicMax(slot + (blockIdx.x & (NSLOT - 1)) * SLOT_U, __float_as_uint(m));
  }
}

// read f16x8 from LDS at 4-byte-aligned (not 16-byte-aligned) address
__device__ inline f16x8 lds_ld8(const _Float16* p) {
  union { unsigned u[4]; f16x8 h; } r;
  const unsigned* q = (const unsigned*)p;
  r.u[0] = q[0]; r.u[1] = q[1]; r.u[2] = q[2]; r.u[3] = q[3];
  return r.h;
}

// 1x1 conv as integer-exact f16 MFMA GEMM: out[co][pos] = s_in*s_w * sum_ci rw[co][ci]*rx[ci][pos]
// block: 128 positions x 64 co; 4 waves, wave w handles co [16w,16w+16)
__global__ __launch_bounds__(256) void conv1x1_kernel(
    const float* __restrict__ in, float* __restrict__ out,
    const _Float16* __restrict__ wq, const float* __restrict__ sw_ptr,
    const unsigned* __restrict__ sin_slots, unsigned* __restrict__ amax_slots) {
  __shared__ _Float16 lds_x[128 * LDSX_S];   // [pos][ci], stride 66
  __shared__ float wred[4];

  const int tid = threadIdx.x;
  const int p0 = blockIdx.x * 128;
  const int b = p0 >> 16;          // HWSZ = 65536 positions per batch-plane
  const int hw0 = p0 & 65535;
  const float* xin = in + (size_t)b * C64 * HWSZ + hw0;

  const int wv = tid >> 6;
  const int lane = tid & 63;
  const int l15 = lane & 15;
  const int quad = lane >> 4;
  const int cw = wv * 16;

  // input scale from 64-slot spread array (one lane-indexed load + shuffles)
  const float amax_in = slots_amax_wave(sin_slots);
  const float s_in = amax_in / 127.f + 1e-12f;
  const float inv_s = 1.f / s_in;

  // A fragments (integer weight levels) straight from global: 8 KB, L2 resident.
  // A[m=lane&15][k=quad*8+j], k = ci
  f16x8 a0 = *(const f16x8*)(wq + (cw + l15) * 64 + quad * 8);
  f16x8 a1 = *(const f16x8*)(wq + (cw + l15) * 64 + 32 + quad * 8);

  // staging: load -> quantize to integer level -> LDS [pos][ci] stride 66
  // iter i: wave wv covers full 128-pos row of ci = i*4 + wv, lane -> pos 2*lane
  #pragma unroll
  for (int i = 0; i < 16; i++) {
    const int idx = i * 256 + tid;
    const int ci = idx >> 6;            // wave-uniform
    const int pz = (idx & 63) * 2;      // per-lane position
    float2 v = *(const float2*)(xin + (size_t)ci * HWSZ + pz);
    float r0 = fminf(fmaxf(rintf(v.x * inv_s), -127.f), 127.f);
    float r1 = fminf(fmaxf(rintf(v.y * inv_s), -127.f), 127.f);
    lds_x[(pz + 0) * LDSX_S + ci] = (_Float16)r0;
    lds_x[(pz + 1) * LDSX_S + ci] = (_Float16)r1;
  }
  __syncthreads();

  f32x4 acc[8];
  #pragma unroll
  for (int nt = 0; nt < 8; nt++) {
    const _Float16* bp = lds_x + (nt * 16 + l15) * LDSX_S + quad * 8;
    f16x8 b0 = lds_ld8(bp);        // B[k=quad*8+j][n=l15], k = ci
    f16x8 b1 = lds_ld8(bp + 32);
    f32x4 c = {0.f, 0.f, 0.f, 0.f};
    c = __builtin_amdgcn_mfma_f32_16x16x32_f16(a0, b0, c, 0, 0, 0);
    c = __builtin_amdgcn_mfma_f32_16x16x32_f16(a1, b1, c, 0, 0, 0);
    acc[nt] = c;
  }

  const float sw = *sw_ptr;
  const float sout = s_in * sw;
  float m = 0.f;
  float* outb = out + (size_t)b * C64 * HWSZ + hw0;
  #pragma unroll
  for (int nt = 0; nt < 8; nt++) {
    const int pp = nt * 16 + l15;
    #pragma unroll
    for (int r = 0; r < 4; r++) {
      const int co = cw + quad * 4 + r;   // C layout: col=lane&15, row=quad*4+reg
      float vv = acc[nt][r] * sout;
      outb[(size_t)co * HWSZ + pp] = vv;
      m = fmaxf(m, fabsf(vv));
    }
  }
  for (int off = 32; off; off >>= 1) m = fmaxf(m, __shfl_down(m, off));
  if (lane == 0) wred[wv] = m;
  __syncthreads();
  if (tid == 0)
    atomicMax(amax_slots + (blockIdx.x & (NSLOT - 1)) * SLOT_U,
              __float_as_uint(fmaxf(fmaxf(wred[0], wred[1]), fmaxf(wred[2], wred[3]))));
}

// depthwise 3x3 (quantized input) + prelu (+ optional residual) (+ optional amax)
template <bool FUSE_RES>
__global__ __launch_bounds__(256) void dwconv_kernel(
    const float* __restrict__ in, float* __restrict__ out,
    const float* __restrict__ wq9, const float* __restrict__ alpha,
    const unsigned* __restrict__ sin_slots, unsigned* __restrict__ amax_slots,
    const float* __restrict__ resid) {
  __shared__ float wred[4];
  const int strip = blockIdx.x & 7;        // 8 strips of 32 rows
  const int bc = blockIdx.x >> 3;          // 0..1023
  const int ch = bc & 63;
  const float* W9 = wq9 + ch * 9;
  const float w00 = W9[0], w01 = W9[1], w02 = W9[2];
  const float w10 = W9[3], w11 = W9[4], w12 = W9[5];
  const float w20 = W9[6], w21 = W9[7], w22 = W9[8];
  const float al = alpha[ch];
  const float amax_in = slots_amax_wave(sin_slots);
  const float s = amax_in / 127.f + 1e-12f;
  const float inv_s = 1.f / s;
  const float* base = in + (size_t)bc * HWSZ;
  float* ob = out + (size_t)bc * HWSZ;
  const float* rb = resid + (size_t)bc * HWSZ;   // only read if FUSE_RES
  const int c = threadIdx.x;                     // column 0..255
  const int r0 = strip * 32;

  auto qz = [&](float v) {
    return fminf(fmaxf(rintf(v * inv_s), -127.f), 127.f) * s;
  };

  float aL, aC, aR, bL, bC, bR, cL, cC, cR;
  auto ldrow = [&](int r, float& L, float& Cv, float& R) {
    if ((unsigned)r > 255u) { L = 0.f; Cv = 0.f; R = 0.f; return; }
    const float* rp = base + r * 256;
    Cv = qz(rp[c]);
    L = (c > 0) ? qz(rp[c - 1]) : 0.f;
    R = (c < 255) ? qz(rp[c + 1]) : 0.f;
  };

  ldrow(r0 - 1, aL, aC, aR);
  ldrow(r0, bL, bC, bR);
  float m = 0.f;
  for (int r = r0; r < r0 + 32; r++) {
    ldrow(r + 1, cL, cC, cR);
    float o = w00 * aL + w01 * aC + w02 * aR
            + w10 * bL + w11 * bC + w12 * bR
            + w20 * cL + w21 * cC + w22 * cR;
    o = (o > 0.f) ? o : al * o;
    if (FUSE_RES) o += rb[r * 256 + c];
    ob[r * 256 + c] = o;
    m = fmaxf(m, fabsf(o));
    aL = bL; aC = bC; aR = bR;
    bL = cL; bC = cC; bR = cR;
  }
  if (amax_slots != nullptr) {
    for (int off = 32; off; off >>= 1) m = fmaxf(m, __shfl_down(m, off));
    if ((c & 63) == 0) wred[c >> 6] = m;
    __syncthreads();
    if (c == 0)
      atomicMax(amax_slots + (blockIdx.x & (NSLOT - 1)) * SLOT_U,
                __float_as_uint(fmaxf(fmaxf(wred[0], wred[1]), fmaxf(wred[2], wred[3]))));
  }
}

extern "C" void kernel_launch(void* const* d_in, const int* in_sizes, int n_in,
                              void* d_out, int out_size, void* d_ws, size_t ws_size,
                              hipStream_t stream) {
  const float* x   = (const float*)d_in[0];
  const float* wp1 = (const float*)d_in[1];
  const float* wf1 = (const float*)d_in[2];
  const float* wp2 = (const float*)d_in[3];
  const float* wf2 = (const float*)d_in[4];
  const float* al1 = (const float*)d_in[5];
  const float* al2 = (const float*)d_in[6];
  float* out = (float*)d_out;

  char* ws = (char*)d_ws;
  unsigned* slots   = (unsigned*)(ws + OFF_SLOTS);
  float* scales     = (float*)(ws + OFF_SCALES);
  _Float16* wqp1    = (_Float16*)(ws + OFF_WQP1);
  _Float16* wqp2    = (_Float16*)(ws + OFF_WQP2);
  float* wqf1       = (float*)(ws + OFF_WQF1);
  float* wqf2       = (float*)(ws + OFF_WQF2);
  float* buf        = (float*)(ws + OFF_BUF);

  unsigned* sl0 = slots + 0 * NSLOT * SLOT_U;   // amax(x)
  unsigned* sl1 = slots + 1 * NSLOT * SLOT_U;   // amax(y1)
  unsigned* sl2 = slots + 2 * NSLOT * SLOT_U;   // amax(y3)
  unsigned* sl3 = slots + 3 * NSLOT * SLOT_U;   // amax(y4)

  // 1. weight quant + slot init
  prep_kernel<<<1, 256, 0, stream>>>(wp1, wf1, wp2, wf2, slots, scales,
                                     wqp1, wqp2, wqf1, wqf2);
  // 2. amax(x) -> sl0
  amax_kernel<<<4096, 256, 0, stream>>>((const float4*)x, NTOT / 4, sl0);
  // 3. p1: x -> buf (y1), amax -> sl1
  conv1x1_kernel<<<NTOT / C64 / 128, 256, 0, stream>>>(x, buf, wqp1, scales + 0,
                                                       sl0, sl1);
  // 4. dw1 + prelu: buf -> out (y3), amax -> sl2
  dwconv_kernel<false><<<NBATCH * C64 * 8, 256, 0, stream>>>(buf, out, wqf1, al1,
                                                             sl1, sl2, nullptr);
  // 5. p2: out -> buf (y4), amax -> sl3
  conv1x1_kernel<<<NTOT / C64 / 128, 256, 0, stream>>>(out, buf, wqp2, scales + 2,
                                                       sl2, sl3);
  // 6. dw2 + prelu + residual: buf + x -> out
  dwconv_kernel<true><<<NBATCH * C64 * 8, 256, 0, stream>>>(buf, out, wqf2, al2,
                                                            sl3, nullptr, x);
}